// Round 1
// baseline (1503.357 us; speedup 1.0000x reference)
//
#include <hip/hip_runtime.h>

// Problem constants (fixed shapes from setup_inputs)
#define BATCH 16
#define CHAN 192
#define IMG_HW (224*224)   // 50176 pixels
#define NSEG 196
#define CB 16              // channels per accum block
#define SPLIT 7            // tile-splits per (b, c-group); 49 tiles / 7 = 7 tiles/block
#define NTILES 49          // 50176 / 1024
#define TILE_PX 1024
#define PAD 17             // NSEG row stride in LDS (odd -> banks spread)

__global__ __launch_bounds__(256) void count_kernel(const int* __restrict__ seg,
                                                    int* __restrict__ counts) {
    __shared__ int cnt[NSEG];
    const int tid = threadIdx.x;
    if (tid < NSEG) cnt[tid] = 0;
    __syncthreads();
    const int b = blockIdx.y;
    const int tile = blockIdx.x;
    const int4* sp = (const int4*)(seg + (size_t)b * IMG_HW + tile * TILE_PX);
    int4 s4 = sp[tid];
    atomicAdd(&cnt[s4.x], 1);
    atomicAdd(&cnt[s4.y], 1);
    atomicAdd(&cnt[s4.z], 1);
    atomicAdd(&cnt[s4.w], 1);
    __syncthreads();
    if (tid < NSEG) atomicAdd(&counts[b * NSEG + tid], cnt[tid]);
}

__global__ __launch_bounds__(256) void accum_kernel(const float* __restrict__ feat,
                                                    const int* __restrict__ seg,
                                                    float* __restrict__ out_sums) {
    __shared__ float ssum[NSEG * PAD];   // 196*17*4 = 13.3 KB
    __shared__ int   sseg[TILE_PX];      // 4 KB
    const int tid = threadIdx.x;
    for (int i = tid; i < NSEG * PAD; i += 256) ssum[i] = 0.0f;

    const int b     = blockIdx.z;
    const int cbase = blockIdx.y * CB;

    for (int tile = blockIdx.x; tile < NTILES; tile += SPLIT) {
        __syncthreads();  // protects sseg overwrite AND covers initial ssum zeroing
        const int4* sp = (const int4*)(seg + (size_t)b * IMG_HW + tile * TILE_PX);
        ((int4*)sseg)[tid] = sp[tid];
        __syncthreads();
        const float* fb = feat + ((size_t)b * CHAN + cbase) * IMG_HW + tile * TILE_PX;
        const int p = tid * 4;
        const int s0 = sseg[p + 0] * PAD;
        const int s1 = sseg[p + 1] * PAD;
        const int s2 = sseg[p + 2] * PAD;
        const int s3 = sseg[p + 3] * PAD;
        #pragma unroll 4
        for (int cl = 0; cl < CB; ++cl) {
            const float4* fp = (const float4*)(fb + (size_t)cl * IMG_HW);
            float4 v = fp[tid];
            atomicAdd(&ssum[s0 + cl], v.x);
            atomicAdd(&ssum[s1 + cl], v.y);
            atomicAdd(&ssum[s2 + cl], v.z);
            atomicAdd(&ssum[s3 + cl], v.w);
        }
    }
    __syncthreads();
    for (int i = tid; i < NSEG * CB; i += 256) {
        const int s  = i / CB;
        const int cl = i % CB;
        atomicAdd(&out_sums[((size_t)b * NSEG + s) * CHAN + cbase + cl],
                  ssum[s * PAD + cl]);
    }
}

__global__ __launch_bounds__(256) void finalize_kernel(float* __restrict__ out,
                                                       const int* __restrict__ counts,
                                                       const float* __restrict__ coords,
                                                       const float* __restrict__ posW,
                                                       const float* __restrict__ posb) {
    const int idx = blockIdx.x * 256 + threadIdx.x;
    if (idx >= BATCH * NSEG * CHAN) return;
    const int c = idx % CHAN;
    const int s = (idx / CHAN) % NSEG;
    const int b = idx / (CHAN * NSEG);
    const float cntf = (float)max(counts[b * NSEG + s], 1);
    const float x = coords[(b * NSEG + s) * 2 + 0] * (1.0f / 224.0f);
    const float y = coords[(b * NSEG + s) * 2 + 1] * (1.0f / 224.0f);
    const float pos = x * posW[c] + y * posW[CHAN + c] + posb[c];
    out[idx] = out[idx] / cntf + pos;
}

extern "C" void kernel_launch(void* const* d_in, const int* in_sizes, int n_in,
                              void* d_out, int out_size, void* d_ws, size_t ws_size,
                              hipStream_t stream) {
    // inputs: 0=img (unused), 1=features f32, 2=segments int, 3=centroid_coords f32,
    //         4=pos_W f32 (2,C), 5=pos_b f32 (C), 6=max_segments scalar
    const float* feat   = (const float*)d_in[1];
    const int*   seg    = (const int*)d_in[2];
    const float* coords = (const float*)d_in[3];
    const float* posW   = (const float*)d_in[4];
    const float* posb   = (const float*)d_in[5];
    float* out = (float*)d_out;
    int* counts = (int*)d_ws;   // BATCH*NSEG ints

    hipMemsetAsync(out, 0, (size_t)BATCH * NSEG * CHAN * sizeof(float), stream);
    hipMemsetAsync(counts, 0, (size_t)BATCH * NSEG * sizeof(int), stream);

    count_kernel<<<dim3(NTILES, BATCH), 256, 0, stream>>>(seg, counts);
    accum_kernel<<<dim3(SPLIT, CHAN / CB, BATCH), 256, 0, stream>>>(feat, seg, out);

    const int n = BATCH * NSEG * CHAN;
    finalize_kernel<<<dim3((n + 255) / 256), 256, 0, stream>>>(out, counts, coords, posW, posb);
}

// Round 2
// 933.203 us; speedup vs baseline: 1.6110x; 1.6110x over previous
//
#include <hip/hip_runtime.h>

// Shapes fixed by setup_inputs()
#define BATCH 16
#define CHAN 192
#define HW 50176            // 224*224
#define NSEG 196
#define NSEGT 13            // ceil(196/16) seg-tiles (208 padded; rows >=196 are all-zero)
#define PIXSPLIT 8
#define PPB (HW / PIXSPLIT) // 6272 pixels per block
#define KSTEPS (PPB / 32)   // 196 k-steps of 32 pixels

typedef __attribute__((ext_vector_type(8))) short short8; // 8 bf16 = one MFMA A/B frag
typedef __attribute__((ext_vector_type(4))) float f32x4;
typedef __attribute__((ext_vector_type(4))) int   i32x4;

__device__ __forceinline__ short bfc(float x) {            // f32 -> bf16, round-half-up
    unsigned u = __float_as_uint(x);
    return (short)((u + 0x8000u) >> 16);
}

// One-hot MFMA segment-sum. Grid (PIXSPLIT, 2, BATCH), block 384 (6 waves).
// Wave w owns channel group cbase=(by*6+w)*16, all 13 seg-tiles.
// A-frags (one-hot) built cooperatively in LDS once per k-step, shared by all 6 waves.
__global__ __launch_bounds__(384, 3) void accum_mfma(
        const float* __restrict__ feat,
        const int*   __restrict__ seg,
        float*       __restrict__ out) {
    __shared__ short8 abuf[NSEGT * 64];   // 13 tiles x 64 lanes x 16B = 13.3 KB

    const int tid  = threadIdx.x;
    const int wave = tid >> 6;
    const int lane = tid & 63;
    const int quad = lane >> 4;
    const int m    = lane & 15;

    const int b      = blockIdx.z;
    const int cbase  = (blockIdx.y * 6 + wave) * 16;
    const int pstart = blockIdx.x * PPB;

    const int*   sptr = seg  + (size_t)b * HW + pstart;
    const float* fptr = feat + ((size_t)b * CHAN + cbase + m) * HW + pstart;

    f32x4 acc[NSEGT];
#pragma unroll
    for (int t = 0; t < NSEGT; ++t) acc[t] = (f32x4)0.0f;

    // prologue loads (k-step 0); software-pipelined by one k-step
    i32x4 s0 = *(const i32x4*)(sptr + quad * 8);
    i32x4 s1 = *(const i32x4*)(sptr + quad * 8 + 4);
    f32x4 f0 = *(const f32x4*)(fptr + quad * 8);
    f32x4 f1 = *(const f32x4*)(fptr + quad * 8 + 4);

    for (int kk = 0; kk < KSTEPS; ++kk) {
        __syncthreads();                         // WAR: prior reads of abuf done
        const int sv[8] = {s0.x, s0.y, s0.z, s0.w, s1.x, s1.y, s1.z, s1.w};
        // build A: A[m=lane&15][k=quad*8+j] = (seg[pbase+k] == 16t+m) ? 1.0bf : 0
        for (int t = wave; t < NSEGT; t += 6) {
            const int target = t * 16 + m;
            short8 af;
#pragma unroll
            for (int j = 0; j < 8; ++j)
                af[j] = (sv[j] == target) ? (short)0x3F80 : (short)0;
            abuf[t * 64 + lane] = af;
        }
        __syncthreads();

        // B frag: B[k=quad*8+j][n=lane&15] = feat[cbase+n][pbase+k] (bf16)
        short8 bf;
        bf[0] = bfc(f0.x); bf[1] = bfc(f0.y); bf[2] = bfc(f0.z); bf[3] = bfc(f0.w);
        bf[4] = bfc(f1.x); bf[5] = bfc(f1.y); bf[6] = bfc(f1.z); bf[7] = bfc(f1.w);

        // prefetch next k-step while MFMA runs (last iter reloads current: harmless)
        const int pn = (kk + 1 < KSTEPS ? kk + 1 : kk) * 32;
        s0 = *(const i32x4*)(sptr + pn + quad * 8);
        s1 = *(const i32x4*)(sptr + pn + quad * 8 + 4);
        f0 = *(const f32x4*)(fptr + pn + quad * 8);
        f1 = *(const f32x4*)(fptr + pn + quad * 8 + 4);

#pragma unroll
        for (int t = 0; t < NSEGT; ++t) {
            short8 af = abuf[t * 64 + lane];
            acc[t] = __builtin_amdgcn_mfma_f32_16x16x32_bf16(af, bf, acc[t], 0, 0, 0);
        }
    }

    // C/D layout: col(c) = lane&15, row(s_local) = quad*4 + reg
    float* obase = out + ((size_t)b * NSEG) * CHAN + cbase + m;
#pragma unroll
    for (int t = 0; t < NSEGT; ++t) {
#pragma unroll
        for (int r = 0; r < 4; ++r) {
            const int s = t * 16 + quad * 4 + r;
            if (s < NSEG) atomicAdd(obase + (size_t)s * CHAN, acc[t][r]);
        }
    }
}

__global__ __launch_bounds__(256) void count_kernel(const int* __restrict__ seg,
                                                    int* __restrict__ counts) {
    __shared__ int cnt[NSEG];
    const int tid = threadIdx.x;
    if (tid < NSEG) cnt[tid] = 0;
    __syncthreads();
    const int b = blockIdx.y;
    const int4* sp = (const int4*)(seg + (size_t)b * HW + blockIdx.x * 1024);
    int4 s4 = sp[tid];
    atomicAdd(&cnt[s4.x], 1);
    atomicAdd(&cnt[s4.y], 1);
    atomicAdd(&cnt[s4.z], 1);
    atomicAdd(&cnt[s4.w], 1);
    __syncthreads();
    if (tid < NSEG) atomicAdd(&counts[b * NSEG + tid], cnt[tid]);
}

__global__ __launch_bounds__(256) void finalize_kernel(float* __restrict__ out,
                                                       const int* __restrict__ counts,
                                                       const float* __restrict__ coords,
                                                       const float* __restrict__ posW,
                                                       const float* __restrict__ posb) {
    const int idx = blockIdx.x * 256 + threadIdx.x;
    if (idx >= BATCH * NSEG * CHAN) return;
    const int c = idx % CHAN;
    const int s = (idx / CHAN) % NSEG;
    const int b = idx / (CHAN * NSEG);
    const float cntf = (float)max(counts[b * NSEG + s], 1);
    const float x = coords[(b * NSEG + s) * 2 + 0] * (1.0f / 224.0f);
    const float y = coords[(b * NSEG + s) * 2 + 1] * (1.0f / 224.0f);
    const float pos = x * posW[c] + y * posW[CHAN + c] + posb[c];
    out[idx] = out[idx] / cntf + pos;
}

extern "C" void kernel_launch(void* const* d_in, const int* in_sizes, int n_in,
                              void* d_out, int out_size, void* d_ws, size_t ws_size,
                              hipStream_t stream) {
    const float* feat   = (const float*)d_in[1];
    const int*   seg    = (const int*)d_in[2];
    const float* coords = (const float*)d_in[3];
    const float* posW   = (const float*)d_in[4];
    const float* posb   = (const float*)d_in[5];
    float* out    = (float*)d_out;
    int*   counts = (int*)d_ws;   // BATCH*NSEG ints

    hipMemsetAsync(out, 0, (size_t)BATCH * NSEG * CHAN * sizeof(float), stream);
    hipMemsetAsync(counts, 0, (size_t)BATCH * NSEG * sizeof(int), stream);

    count_kernel<<<dim3(HW / 1024, BATCH), 256, 0, stream>>>(seg, counts);
    accum_mfma<<<dim3(PIXSPLIT, 2, BATCH), 384, 0, stream>>>(feat, seg, out);

    const int n = BATCH * NSEG * CHAN;
    finalize_kernel<<<dim3((n + 255) / 256), 256, 0, stream>>>(out, counts, coords, posW, posb);
}